// Round 18
// baseline (148.315 us; speedup 1.0000x reference)
//
#include <hip/hip_runtime.h>
#include <cstdint>

#define EPSV 1e-5f
#define SM_SCALE 0.044194173824159216f

typedef unsigned short u16;
typedef __attribute__((ext_vector_type(8))) short short8;
typedef __attribute__((ext_vector_type(4))) float f32x4;

__device__ __forceinline__ u16 f2bf(float f) {
  union { float f; uint32_t u; } v; v.f = f;
  return (u16)((v.u + 0x7FFFu + ((v.u >> 16) & 1u)) >> 16);
}

__device__ __forceinline__ void gload_lds16(const void* g, void* l) {
  __builtin_amdgcn_global_load_lds((const __attribute__((address_space(1))) void*)g,
                                   (__attribute__((address_space(3))) void*)l, 16, 0, 0);
}

__device__ __forceinline__ f32x4 mfma16(short8 a, short8 b, f32x4 c) {
  return __builtin_amdgcn_mfma_f32_16x16x32_bf16(a, b, c, 0, 0, 0);
}

// ---------- Fused GroupNorm ----------
__global__ __launch_bounds__(256) void gn_fused_k(const float* __restrict__ x,
                                                  const float* __restrict__ gw,
                                                  const float* __restrict__ gb,
                                                  u16* __restrict__ xn) {
  __shared__ float xs[8192];
  __shared__ float ls[4], lss[4];
  const int bg = blockIdx.x;
  const int g = bg & 31;
  const float* p = x + (size_t)bg * 8192;
  float s = 0.f, ss = 0.f;
#pragma unroll
  for (int i = 0; i < 8; ++i) {
    const int idx = i * 1024 + threadIdx.x * 4;
    float4 v = *reinterpret_cast<const float4*>(p + idx);
    *reinterpret_cast<float4*>(xs + idx) = v;
    s += v.x + v.y + v.z + v.w;
    ss += v.x * v.x + v.y * v.y + v.z * v.z + v.w * v.w;
  }
  for (int off = 32; off; off >>= 1) { s += __shfl_xor(s, off); ss += __shfl_xor(ss, off); }
  const int w = threadIdx.x >> 6;
  if ((threadIdx.x & 63) == 0) { ls[w] = s; lss[w] = ss; }
  __syncthreads();
  s = ls[0] + ls[1] + ls[2] + ls[3];
  ss = lss[0] + lss[1] + lss[2] + lss[3];
  const float inv_n = 1.0f / 8192.f;
  const float mean = s * inv_n;
  const float rstd = rsqrtf(ss * inv_n - mean * mean + EPSV);
#pragma unroll
  for (int j = 0; j < 4; ++j) {
    const int idx = j * 2048 + threadIdx.x * 8;
    const int c = g * 16 + (idx >> 9);
    const float sc = gw[c] * rstd;
    const float sh = gb[c] - mean * sc;
    u16 o[8];
#pragma unroll
    for (int e = 0; e < 8; ++e) o[e] = f2bf(xs[idx + e] * sc + sh);
    *reinterpret_cast<uint4*>(xn + (size_t)bg * 8192 + idx) = *reinterpret_cast<const uint4*>(o);
  }
}

// ---------- weight casts ----------
__global__ __launch_bounds__(256) void cast3_k(const float* __restrict__ a,
                                               const float* __restrict__ b2,
                                               const float* __restrict__ c,
                                               u16* __restrict__ oa, u16* __restrict__ ob,
                                               u16* __restrict__ oc) {
  const int which = blockIdx.x >> 7;
  const float* in = which == 0 ? a : (which == 1 ? b2 : c);
  u16* out = which == 0 ? oa : (which == 1 ? ob : oc);
  size_t base = (((size_t)(blockIdx.x & 127)) * 256 + threadIdx.x) * 8;
  float4 v0 = *reinterpret_cast<const float4*>(in + base);
  float4 v1 = *reinterpret_cast<const float4*>(in + base + 4);
  u16 o[8];
  o[0] = f2bf(v0.x); o[1] = f2bf(v0.y); o[2] = f2bf(v0.z); o[3] = f2bf(v0.w);
  o[4] = f2bf(v1.x); o[5] = f2bf(v1.y); o[6] = f2bf(v1.z); o[7] = f2bf(v1.w);
  *reinterpret_cast<uint4*>(out + base) = *reinterpret_cast<const uint4*>(o);
}

// ---------- 8-phase 256^2 GEMM (R17 verified, unchanged) ----------
template <int OUT_MODE>
__global__ __launch_bounds__(512, 1) void gemm256_k(const u16* __restrict__ A, size_t sA,
                                                    const u16* __restrict__ Bm, size_t sB,
                                                    const float* __restrict__ bias,
                                                    void* __restrict__ out, size_t sO) {
  __shared__ u16 smem[65536];
  const int d = blockIdx.x;
  const int wgid = (d & 7) * 32 + (d >> 3);
  const int b = wgid >> 2;
  const int tile = wgid & 3;
  const int tm = (tile >> 1) * 256, tn = (tile & 1) * 256;
  const u16* Ab = A + (size_t)b * sA;
  const u16* Bb = Bm + (size_t)b * sB;
  const int tid = threadIdx.x, w = tid >> 6, lane = tid & 63;
  const int rh = w >> 2, cw = w & 3;
  const int frow = lane & 15, cc = lane >> 4;
  f32x4 acc[8][4] = {};
  short8 af[8], bfr[2];

#define STAGEH(Lofs, Gp)                                                       \
  {                                                                            \
    const u16* gsrc_ = (Gp);                                                   \
    _Pragma("unroll")                                                          \
    for (int p_ = 0; p_ < 2; ++p_) {                                           \
      const int row_ = p_ * 64 + (tid >> 3);                                   \
      const int slot_ = (tid & 7) ^ (row_ & 7);                                \
      gload_lds16(gsrc_ + (size_t)row_ * 512 + slot_ * 8,                      \
                  &smem[(Lofs) + p_ * 4096 + tid * 8]);                        \
    }                                                                          \
  }

#define PHASE(VMN, QB, KS, CP, ...)                                            \
  {                                                                            \
    asm volatile("s_waitcnt vmcnt(" #VMN ")" ::: "memory");                    \
    __builtin_amdgcn_s_barrier();                                              \
    asm volatile("" ::: "memory");                                             \
    _Pragma("unroll")                                                          \
    for (int j_ = 0; j_ < 2; ++j_) {                                           \
      const int lrb_ = (cw & 1) * 64 + (CP) * 32 + j_ * 16 + frow;             \
      bfr[j_] = *reinterpret_cast<const short8*>(                              \
          &smem[(QB) + 16384 + (cw >> 1) * 8192 + lrb_ * 64 +                  \
                (((KS) * 4 + cc) ^ (lrb_ & 7)) * 8]);                          \
    }                                                                          \
    if ((CP) == 0) {                                                           \
      _Pragma("unroll")                                                        \
      for (int ri_ = 0; ri_ < 8; ++ri_) {                                      \
        const int lra_ = ri_ * 16 + frow;                                      \
        af[ri_] = *reinterpret_cast<const short8*>(                            \
            &smem[(QB) + rh * 8192 + lra_ * 64 +                               \
                  (((KS) * 4 + cc) ^ (lra_ & 7)) * 8]);                        \
      }                                                                        \
    }                                                                          \
    __VA_ARGS__                                                                \
    __builtin_amdgcn_s_setprio(1);                                             \
    _Pragma("unroll")                                                          \
    for (int ri_ = 0; ri_ < 8; ++ri_) {                                        \
      acc[ri_][(CP) * 2]     = mfma16(af[ri_], bfr[0], acc[ri_][(CP) * 2]);    \
      acc[ri_][(CP) * 2 + 1] = mfma16(af[ri_], bfr[1], acc[ri_][(CP) * 2 + 1]);\
    }                                                                          \
    __builtin_amdgcn_s_setprio(0);                                             \
    __builtin_amdgcn_s_barrier();                                              \
    asm volatile("" ::: "memory");                                             \
  }

  STAGEH(0,     Ab + (size_t)tm * 512);
  STAGEH(8192,  Ab + (size_t)(tm + 128) * 512);
  STAGEH(16384, Bb + (size_t)tn * 512);
  STAGEH(24576, Bb + (size_t)(tn + 128) * 512);
  STAGEH(32768, Ab + (size_t)tm * 512 + 64);

  for (int i = 0; i < 3; ++i) {
    const int k0c1 = i * 128 + 64;
    const int k0n2 = i * 128 + 128;
    const int k0n3 = i * 128 + 192;
    PHASE(2, 0, 0, 0,
          STAGEH(40960, Ab + (size_t)(tm + 128) * 512 + k0c1);
          STAGEH(49152, Bb + (size_t)tn * 512 + k0c1);)
    PHASE(6, 0, 0, 1,
          STAGEH(57344, Bb + (size_t)(tn + 128) * 512 + k0c1);)
    PHASE(6, 0, 1, 0, )
    PHASE(2, 0, 1, 1,
          STAGEH(0, Ab + (size_t)tm * 512 + k0n2);)
    PHASE(2, 32768, 0, 0,
          STAGEH(8192,  Ab + (size_t)(tm + 128) * 512 + k0n2);
          STAGEH(16384, Bb + (size_t)tn * 512 + k0n2);)
    PHASE(6, 32768, 0, 1,
          STAGEH(24576, Bb + (size_t)(tn + 128) * 512 + k0n2);)
    PHASE(6, 32768, 1, 0, )
    PHASE(2, 32768, 1, 1,
          STAGEH(32768, Ab + (size_t)tm * 512 + k0n3);)
  }
  PHASE(2, 0, 0, 0,
        STAGEH(40960, Ab + (size_t)(tm + 128) * 512 + 448);
        STAGEH(49152, Bb + (size_t)tn * 512 + 448);)
  PHASE(6, 0, 0, 1,
        STAGEH(57344, Bb + (size_t)(tn + 128) * 512 + 448);)
  PHASE(6, 0, 1, 0, )
  PHASE(2, 0, 1, 1, )
  PHASE(0, 32768, 0, 0, )
  PHASE(0, 32768, 0, 1, )
  PHASE(0, 32768, 1, 0, )
  PHASE(0, 32768, 1, 1, )
#undef PHASE
#undef STAGEH

  const int col0 = lane & 15, row0 = (lane >> 4) * 4;
#pragma unroll
  for (int ri = 0; ri < 8; ++ri) {
#pragma unroll
    for (int cj = 0; cj < 4; ++cj) {
      const int gc = tn + cw * 64 + cj * 16 + col0;
      const float bv = (OUT_MODE == 0) ? bias[gc] : 0.f;
#pragma unroll
      for (int r = 0; r < 4; ++r) {
        const int gr = tm + rh * 128 + ri * 16 + row0 + r;
        float v = acc[ri][cj][r];
        if (OUT_MODE == 0) v += bv;
        if (OUT_MODE == 1) v += bias[gr];
        if (OUT_MODE == 2)
          ((float*)out)[(size_t)b * sO + (size_t)gr * 512 + gc] = v;
        else
          ((u16*)out)[(size_t)b * sO + (size_t)gr * 512 + gc] = f2bf(v);
      }
    }
  }
}

// ---------- scores + softmax -> P: 128q x 512k block, 8 waves, triple-buffer ----------
// Wave w = all 128 q-rows x keys w*64..+63; acc[8 rowfrag][4 colfrag] = 128 VGPR.
// BK=32, 3 buffers (no WAR hazard) -> ONE barrier + ONE counted vmcnt(5) per
// k-step, loads never drain. vmcnt ledger: prologue 10 in flight; steady
// outstanding = cur 5 + next 5 -> vmcnt(5) lands cur; ts=15 drains 0. Stage
// for ts+2 issues after ts's entry barrier (all waves done with ts-1 = last
// reader of target buffer). Swizzle slot'=slot^((row>>1)&3) (verified 2-way=free).
__global__ __launch_bounds__(512, 1) void scores_softmax_k(const u16* __restrict__ Q,
                                                           const u16* __restrict__ K,
                                                           u16* __restrict__ P) {
  __shared__ u16 smem[61440];          // 120KB: K bufs m*16384 (3x32KB); Q bufs 49152+m*4096 (3x8KB)
  __shared__ float rmax[128][8], rsum[128][8];   // 8KB
  const int d = blockIdx.x;            // 0..255
  const int wgid = (d & 7) * 32 + (d >> 3);      // XCD-bijective
  const int b = wgid >> 2;
  const int m0 = (wgid & 3) * 128;
  const u16* Qb = Q + (size_t)b * 262144 + (size_t)m0 * 512;
  const u16* Kb = K + (size_t)b * 262144;
  u16* Pb = P + (size_t)b * 262144 + (size_t)m0 * 512;
  const int tid = threadIdx.x, w = tid >> 6, lane = tid & 63;
  const int frow = lane & 15, cc = lane >> 4;
  f32x4 acc[8][4] = {};

  // Stage K-slice 512x32 (4 loads) + Q-slice 128x32 (1 load) for one k-step.
#define KQ_STAGE(m, k0)                                                        \
  {                                                                            \
    _Pragma("unroll")                                                          \
    for (int s2_ = 0; s2_ < 4; ++s2_) {                                        \
      const int idx_ = s2_ * 512 + tid;                                        \
      const int row_ = idx_ >> 2, slot_ = idx_ & 3;                            \
      gload_lds16(Kb + (size_t)row_ * 512 + (k0) + (slot_ ^ ((row_ >> 1) & 3)) * 8, \
                  &smem[(m) * 16384 + idx_ * 8]);                              \
    }                                                                          \
    {                                                                          \
      const int row_ = tid >> 2, slot_ = tid & 3;                              \
      gload_lds16(Qb + (size_t)row_ * 512 + (k0) + (slot_ ^ ((row_ >> 1) & 3)) * 8, \
                  &smem[49152 + (m) * 4096 + tid * 8]);                        \
    }                                                                          \
  }

  KQ_STAGE(0, 0);       // 5 loads/thread
  KQ_STAGE(1, 32);      // 10 in flight
  for (int ts = 0; ts < 16; ++ts) {
    const int m = ts % 3;
    if (ts < 15) { asm volatile("s_waitcnt vmcnt(5)" ::: "memory"); }
    else         { asm volatile("s_waitcnt vmcnt(0)" ::: "memory"); }
    __builtin_amdgcn_s_barrier();
    asm volatile("" ::: "memory");
    const u16* Kbuf = &smem[m * 16384];
    const u16* Qbuf = &smem[49152 + m * 4096];
    short8 af[8], bf[4];
#pragma unroll
    for (int ri = 0; ri < 8; ++ri) {
      const int qrow = ri * 16 + frow;
      af[ri] = *reinterpret_cast<const short8*>(
          &Qbuf[qrow * 32 + ((cc ^ ((qrow >> 1) & 3)) * 8)]);
    }
#pragma unroll
    for (int cj = 0; cj < 4; ++cj) {
      const int krow = w * 64 + cj * 16 + frow;
      bf[cj] = *reinterpret_cast<const short8*>(
          &Kbuf[krow * 32 + ((cc ^ ((krow >> 1) & 3)) * 8)]);
    }
    if (ts < 14) KQ_STAGE((ts + 2) % 3, (ts + 2) * 32);
    __builtin_amdgcn_s_setprio(1);
#pragma unroll
    for (int ri = 0; ri < 8; ++ri)
#pragma unroll
      for (int cj = 0; cj < 4; ++cj)
        acc[ri][cj] = mfma16(af[ri], bf[cj], acc[ri][cj]);
    __builtin_amdgcn_s_setprio(0);
  }
#undef KQ_STAGE

  // ---- softmax over 512 keys: wave-partial (64 keys) + 8-wave LDS combine ----
  float pm[8][4];
#pragma unroll
  for (int ri = 0; ri < 8; ++ri)
#pragma unroll
    for (int r = 0; r < 4; ++r) pm[ri][r] = -1e30f;
#pragma unroll
  for (int ri = 0; ri < 8; ++ri)
#pragma unroll
    for (int cj = 0; cj < 4; ++cj)
#pragma unroll
      for (int r = 0; r < 4; ++r) {
        float v = acc[ri][cj][r] * SM_SCALE;
        acc[ri][cj][r] = v;
        pm[ri][r] = fmaxf(pm[ri][r], v);
      }
#pragma unroll
  for (int off = 1; off < 16; off <<= 1)
#pragma unroll
    for (int ri = 0; ri < 8; ++ri)
#pragma unroll
      for (int r = 0; r < 4; ++r) pm[ri][r] = fmaxf(pm[ri][r], __shfl_xor(pm[ri][r], off));
  if (frow == 0) {
#pragma unroll
    for (int ri = 0; ri < 8; ++ri)
#pragma unroll
      for (int r = 0; r < 4; ++r) rmax[ri * 16 + cc * 4 + r][w] = pm[ri][r];
  }
  __syncthreads();
#pragma unroll
  for (int ri = 0; ri < 8; ++ri)
#pragma unroll
    for (int r = 0; r < 4; ++r) {
      const int row = ri * 16 + cc * 4 + r;
      float4 a = *reinterpret_cast<const float4*>(&rmax[row][0]);
      float4 b4 = *reinterpret_cast<const float4*>(&rmax[row][4]);
      pm[ri][r] = fmaxf(fmaxf(fmaxf(a.x, a.y), fmaxf(a.z, a.w)),
                        fmaxf(fmaxf(b4.x, b4.y), fmaxf(b4.z, b4.w)));
    }
  float ps[8][4];
#pragma unroll
  for (int ri = 0; ri < 8; ++ri)
#pragma unroll
    for (int r = 0; r < 4; ++r) ps[ri][r] = 0.f;
#pragma unroll
  for (int ri = 0; ri < 8; ++ri)
#pragma unroll
    for (int cj = 0; cj < 4; ++cj)
#pragma unroll
      for (int r = 0; r < 4; ++r) {
        float e = __expf(acc[ri][cj][r] - pm[ri][r]);
        acc[ri][cj][r] = e;
        ps[ri][r] += e;
      }
#pragma unroll
  for (int off = 1; off < 16; off <<= 1)
#pragma unroll
    for (int ri = 0; ri < 8; ++ri)
#pragma unroll
      for (int r = 0; r < 4; ++r) ps[ri][r] += __shfl_xor(ps[ri][r], off);
  if (frow == 0) {
#pragma unroll
    for (int ri = 0; ri < 8; ++ri)
#pragma unroll
      for (int r = 0; r < 4; ++r) rsum[ri * 16 + cc * 4 + r][w] = ps[ri][r];
  }
  __syncthreads();
#pragma unroll
  for (int ri = 0; ri < 8; ++ri)
#pragma unroll
    for (int r = 0; r < 4; ++r) {
      const int row = ri * 16 + cc * 4 + r;
      float4 a = *reinterpret_cast<const float4*>(&rsum[row][0]);
      float4 b4 = *reinterpret_cast<const float4*>(&rsum[row][4]);
      ps[ri][r] = 1.0f / (a.x + a.y + a.z + a.w + b4.x + b4.y + b4.z + b4.w);
    }
#pragma unroll
  for (int ri = 0; ri < 8; ++ri)
#pragma unroll
    for (int cj = 0; cj < 4; ++cj) {
      const int gcol = w * 64 + cj * 16 + frow;
#pragma unroll
      for (int r = 0; r < 4; ++r) {
        const int grow = ri * 16 + cc * 4 + r;
        Pb[(size_t)grow * 512 + gcol] = f2bf(acc[ri][cj][r] * ps[ri][r]);
      }
    }
}

extern "C" void kernel_launch(void* const* d_in, const int* in_sizes, int n_in,
                              void* d_out, int out_size, void* d_ws, size_t ws_size,
                              hipStream_t stream) {
  const float* x = (const float*)d_in[0];
  const float* qw = (const float*)d_in[1];
  const float* qb = (const float*)d_in[2];
  const float* kw = (const float*)d_in[3];
  const float* kb = (const float*)d_in[4];
  const float* vw = (const float*)d_in[5];
  const float* vb = (const float*)d_in[6];
  const float* gnw = (const float*)d_in[7];
  const float* gnb = (const float*)d_in[8];

  char* ws = (char*)d_ws;
  u16* qwb = (u16*)(ws);
  u16* kwb = (u16*)(ws + 524288);
  u16* vwb = (u16*)(ws + 2 * 524288);
  u16* xn = (u16*)(ws + 4 * 524288);
  u16* Qb = xn + 16777216;
  u16* Kb = Qb + 16777216;
  u16* VT = Kb + 16777216;
  u16* P = xn;                       // xn dead after QKV
  float* out = (float*)d_out;

  gn_fused_k<<<dim3(2048), dim3(256), 0, stream>>>(x, gnw, gnb, xn);
  cast3_k<<<dim3(384), dim3(256), 0, stream>>>(qw, kw, vw, qwb, kwb, vwb);
  // Q = xn qw^T + qb ; K = xn kw^T + kb (bf16, col bias)
  gemm256_k<0><<<dim3(256), dim3(512), 0, stream>>>(xn, (size_t)262144, qwb, (size_t)0, qb, (void*)Qb, (size_t)262144);
  gemm256_k<0><<<dim3(256), dim3(512), 0, stream>>>(xn, (size_t)262144, kwb, (size_t)0, kb, (void*)Kb, (size_t)262144);
  // VT[b,d,c] = sum_k vw[d,k] xn[c,k] + vb[d] (bf16, row bias)
  gemm256_k<1><<<dim3(256), dim3(512), 0, stream>>>(vwb, (size_t)0, xn, (size_t)262144, vb, (void*)VT, (size_t)262144);
  // P = softmax(Q K^T * scale)
  scores_softmax_k<<<dim3(256), dim3(512), 0, stream>>>(Qb, Kb, P);
  // out[b,m,n] = sum_k P[m,k] VT[n,k] (f32)
  gemm256_k<2><<<dim3(256), dim3(512), 0, stream>>>(P, (size_t)262144, VT, (size_t)262144, (const float*)nullptr, (void*)out, (size_t)262144);
}